// Round 4
// baseline (193.605 us; speedup 1.0000x reference)
//
#include <hip/hip_runtime.h>
#include <math.h>

#define NEAR0f 1e-8f
#define REGf   0.002f

typedef float __attribute__((ext_vector_type(4))) f32x4;
typedef int   __attribute__((ext_vector_type(4))) i32x4;

// counted vmcnt wait -- literal immediate, memory clobber so no LDS/VMEM op
// crosses it (rule #18: follow with sched_barrier(0))
#define WAITV(n) do { \
    asm volatile("s_waitcnt vmcnt(" #n ")" ::: "memory"); \
    __builtin_amdgcn_sched_barrier(0); \
} while (0)

__device__ __forceinline__ float wave_reduce(float v) {
#pragma unroll
    for (int off = 32; off > 0; off >>= 1)
        v += __shfl_down(v, off, 64);
    return v;
}

// sum of log(selected prob) over 4 elements, tree-summed
__device__ __forceinline__ float nll4(f32x4 p, i32x4 l) {
    float a0 = l.x ? p.x : 1.0f - p.x;
    float a1 = l.y ? p.y : 1.0f - p.y;
    float a2 = l.z ? p.z : 1.0f - p.z;
    float a3 = l.w ? p.w : 1.0f - p.w;
    float g0 = __logf(fmaxf(a0, NEAR0f)) + __logf(fmaxf(a1, NEAR0f));
    float g1 = __logf(fmaxf(a2, NEAR0f)) + __logf(fmaxf(a3, NEAR0f));
    return g0 + g1;
}

__device__ __forceinline__ float sq4(f32x4 a, float acc) {
    return fmaf(a.x, a.x, fmaf(a.y, a.y, fmaf(a.z, a.z, fmaf(a.w, a.w, acc))));
}

// async global->LDS, 16B per lane, dest = wave-uniform base + lane*16
__device__ __forceinline__ void gload16(const void* g, void* l) {
    __builtin_amdgcn_global_load_lds(
        (const __attribute__((address_space(1))) void*)g,
        (__attribute__((address_space(3))) void*)l, 16, 0, 0);
}

// R4: delivered BW pinned at ~2.7 TB/s across occupancy 22->56% and reg-ILP
// 3->16 (R0-R3); the one untested structure is a DEEP ROLLING pipeline with
// counted never-zero vmcnt (T3/T4; R3's drain-to-0 was bursty and regressed).
// global_load_lds sidesteps the compiler's ~4-deep VGPR ceiling: DMA uses no
// VGPRs, so depth is LDS-bound. Per-wave private ring, 4 slots x (1KB p|l4
// + 1KB partner): prologue 4 pairs (8 loads out), steady state waits
// vmcnt(6) (oldest pair only), consumes via ds_read_b128, issues the
// replacement into the just-freed slot. No __syncthreads. 16 waves/CU x 8KB
// = 128 KB outstanding per CU (5.6x the 5.7MB device-wide needed for
// 6.3 TB/s @ 900ns). Unified 20-step list: 16 (p,l) + 4 (w1,w2) pairs.
__global__ __launch_bounds__(256) void reduce_all(
    const f32x4* __restrict__ p4,
    const i32x4* __restrict__ l4,
    const f32x4* __restrict__ w1,
    const f32x4* __restrict__ w2,
    float* __restrict__ acc,
    int n4, int w4)
{
    __shared__ char ring[4][4][2048];   // [wave][slot][1KB A | 1KB B]

    const int tid    = blockIdx.x * blockDim.x + threadIdx.x;
    const int stride = gridDim.x * blockDim.x;
    const int lane   = threadIdx.x & 63;
    const int wv     = threadIdx.x >> 6;

    float nllA = 0.0f, nllB = 0.0f, s1 = 0.0f, s2 = 0.0f;

    if (n4 == 16 * stride && w4 == 4 * stride) {
        // exact tiling: 16 (p,l) x4-pairs + 4 (w1,w2) x4-pairs per thread
        auto issue = [&](int j) {
            char* base = &ring[wv][j & 3][0];
            if (j < 16) {
                gload16(p4 + (size_t)tid + (size_t)j * stride, base);
                gload16(l4 + (size_t)tid + (size_t)j * stride, base + 1024);
            } else {
                const int k = j - 16;
                gload16(w1 + (size_t)tid + (size_t)k * stride, base);
                gload16(w2 + (size_t)tid + (size_t)k * stride, base + 1024);
            }
        };

        issue(0); issue(1); issue(2); issue(3);   // 8 loads outstanding

#pragma unroll
        for (int t = 0; t < 20; ++t) {
            // wait for the OLDEST pair only; 3 pairs (6 loads) stay in flight
            if (t <= 16)      WAITV(6);
            else if (t == 17) WAITV(4);
            else if (t == 18) WAITV(2);
            else              WAITV(0);

            const char* base = &ring[wv][t & 3][0];
            if (t < 16) {
                const f32x4 pv = *(const f32x4*)(base + (size_t)lane * 16);
                const i32x4 lv = *(const i32x4*)(base + 1024 + (size_t)lane * 16);
                if (t & 1) nllB -= nll4(pv, lv);
                else       nllA -= nll4(pv, lv);
            } else {
                const f32x4 av = *(const f32x4*)(base + (size_t)lane * 16);
                const f32x4 bv = *(const f32x4*)(base + 1024 + (size_t)lane * 16);
                s1 = sq4(av, s1);
                s2 = sq4(bv, s2);
            }
            if (t + 4 < 20) issue(t + 4);   // refill the slot just consumed
        }
    } else {
        // generic fallback (grid-stride, plain C)
        for (int i = tid; i < n4; i += stride) nllA -= nll4(p4[i], l4[i]);
        for (int j = tid; j < w4; j += stride) {
            s1 = sq4(w1[j], s1);
            s2 = sq4(w2[j], s2);
        }
    }

    float nll = nllA + nllB;
    nll = wave_reduce(nll);
    s1  = wave_reduce(s1);
    s2  = wave_reduce(s2);

    __shared__ float sm[3][4];
    if (lane == 0) { sm[0][wv] = nll; sm[1][wv] = s1; sm[2][wv] = s2; }
    __syncthreads();
    if (threadIdx.x == 0) {
        atomicAdd(&acc[0], sm[0][0] + sm[0][1] + sm[0][2] + sm[0][3]);
        atomicAdd(&acc[1], sm[1][0] + sm[1][1] + sm[1][2] + sm[1][3]);
        atomicAdd(&acc[2], sm[2][0] + sm[2][1] + sm[2][2] + sm[2][3]);
    }
}

// d_ws is poisoned 0xAA before every launch — zero accumulators ourselves.
__global__ void init_acc(float* acc) {
    acc[0] = 0.0f; acc[1] = 0.0f; acc[2] = 0.0f;
}

__global__ void finalize(const float* __restrict__ acc, float* __restrict__ out,
                         float invN) {
    out[0] = acc[0] * invN + REGf * (sqrtf(acc[1]) + sqrtf(acc[2]));
}

extern "C" void kernel_launch(void* const* d_in, const int* in_sizes, int n_in,
                              void* d_out, int out_size, void* d_ws, size_t ws_size,
                              hipStream_t stream) {
    const float* out1  = (const float*)d_in[0];   // [N,1] fp32
    const int*   label = (const int*)d_in[1];     // [N] int32 (jax x64 off)
    const float* W1    = (const float*)d_in[2];   // [1024,4096] fp32
    const float* W2    = (const float*)d_in[3];   // [4096,1024] fp32

    const int N  = in_sizes[0];
    const int n4 = N / 4;
    const int w4 = in_sizes[2] / 4;               // W1 and W2 same size

    float* acc = (float*)d_ws;

    init_acc<<<1, 1, 0, stream>>>(acc);
    // 1024 blocks x 256: exactly 4 blocks/CU resident (32KB LDS each),
    // 16 waves/CU, per-thread work = 16 p/l pairs + 4 w pairs.
    reduce_all<<<1024, 256, 0, stream>>>(
        (const f32x4*)out1, (const i32x4*)label,
        (const f32x4*)W1,   (const f32x4*)W2,
        acc, n4, w4);
    finalize<<<1, 1, 0, stream>>>(acc, (float*)d_out, 1.0f / (float)N);
}

// Round 5
// 166.165 us; speedup vs baseline: 1.1651x; 1.1651x over previous
//
#include <hip/hip_runtime.h>
#include <math.h>

#define NEAR0f 1e-8f
#define REGf   0.002f

typedef float __attribute__((ext_vector_type(4))) f32x4;
typedef int   __attribute__((ext_vector_type(4))) i32x4;

__device__ __forceinline__ f32x4 ntload(const f32x4* p) { return __builtin_nontemporal_load(p); }
__device__ __forceinline__ i32x4 ntload(const i32x4* p) { return __builtin_nontemporal_load(p); }

__device__ __forceinline__ float wave_reduce(float v) {
#pragma unroll
    for (int off = 32; off > 0; off >>= 1)
        v += __shfl_down(v, off, 64);
    return v;
}

// sum of log(selected prob) over 4 elements, tree-summed
__device__ __forceinline__ float nll4(f32x4 p, i32x4 l) {
    float a0 = l.x ? p.x : 1.0f - p.x;
    float a1 = l.y ? p.y : 1.0f - p.y;
    float a2 = l.z ? p.z : 1.0f - p.z;
    float a3 = l.w ? p.w : 1.0f - p.w;
    float g0 = __logf(fmaxf(a0, NEAR0f)) + __logf(fmaxf(a1, NEAR0f));
    float g1 = __logf(fmaxf(a2, NEAR0f)) + __logf(fmaxf(a3, NEAR0f));
    return g0 + g1;
}

__device__ __forceinline__ float sq4(f32x4 a, float acc) {
    return fmaf(a.x, a.x, fmaf(a.y, a.y, fmaf(a.z, a.z, fmaf(a.w, a.w, acc))));
}

// R5: best-of-session combination.
// Evidence R0-R4: delivered read BW pinned at <=2.83 TB/s across five
// structure families (occupancy 22-56%, queue depth 3-16, nt on/off,
// asm-burst, gload_lds counted-vmcnt ring). Empirical device read-path
// ceiling ~3.1 TB/s (m13 copy bench read side); R0's kernel = 90% of it,
// bytes irreducible (160 MiB single-touch, p/label inherently paired).
// So: keep R0's exact kernel (59.3 us, the fastest measured -- compiler's
// own 4-deep rolling schedule beats every hand-built pipeline) and swap in
// R1's proven shell (per-block partials -> no init_acc launch, no atomic
// contention; ~116 us fixed harness overhead, one fewer launch).
__global__ __launch_bounds__(256) void reduce_all(
    const f32x4* __restrict__ p4,
    const i32x4* __restrict__ l4,
    const f32x4* __restrict__ w1,
    const f32x4* __restrict__ w2,
    float* __restrict__ part,
    int n4, int w4)
{
    const int tid    = blockIdx.x * blockDim.x + threadIdx.x;
    const int stride = gridDim.x * blockDim.x;

    float nll0 = 0.0f, nll1 = 0.0f, nll2 = 0.0f, nll3 = 0.0f;
    int i = tid;
    for (; i + 3 * stride < n4; i += 4 * stride) {
        f32x4 p0 = ntload(p4 + i);
        f32x4 p1 = ntload(p4 + i + stride);
        f32x4 p2 = ntload(p4 + i + 2 * stride);
        f32x4 p3 = ntload(p4 + i + 3 * stride);
        i32x4 l0 = ntload(l4 + i);
        i32x4 l1 = ntload(l4 + i + stride);
        i32x4 l2 = ntload(l4 + i + 2 * stride);
        i32x4 l3 = ntload(l4 + i + 3 * stride);
        nll0 -= nll4(p0, l0);
        nll1 -= nll4(p1, l1);
        nll2 -= nll4(p2, l2);
        nll3 -= nll4(p3, l3);
    }
    for (; i < n4; i += stride) {
        nll0 -= nll4(ntload(p4 + i), ntload(l4 + i));
    }
    float nll = (nll0 + nll1) + (nll2 + nll3);

    float s1a = 0.0f, s1b = 0.0f, s2a = 0.0f, s2b = 0.0f;
    int j = tid;
    for (; j + 3 * stride < w4; j += 4 * stride) {
        f32x4 a0 = ntload(w1 + j);
        f32x4 a1 = ntload(w1 + j + stride);
        f32x4 a2 = ntload(w1 + j + 2 * stride);
        f32x4 a3 = ntload(w1 + j + 3 * stride);
        f32x4 b0 = ntload(w2 + j);
        f32x4 b1 = ntload(w2 + j + stride);
        f32x4 b2 = ntload(w2 + j + 2 * stride);
        f32x4 b3 = ntload(w2 + j + 3 * stride);
        s1a = sq4(a0, s1a); s1b = sq4(a1, s1b);
        s1a = sq4(a2, s1a); s1b = sq4(a3, s1b);
        s2a = sq4(b0, s2a); s2b = sq4(b1, s2b);
        s2a = sq4(b2, s2a); s2b = sq4(b3, s2b);
    }
    for (; j < w4; j += stride) {
        s1a = sq4(ntload(w1 + j), s1a);
        s2a = sq4(ntload(w2 + j), s2a);
    }
    float s1 = s1a + s1b;
    float s2 = s2a + s2b;

    nll = wave_reduce(nll);
    s1  = wave_reduce(s1);
    s2  = wave_reduce(s2);

    __shared__ float sm[3][4];
    const int lane = threadIdx.x & 63;
    const int wave = threadIdx.x >> 6;
    if (lane == 0) { sm[0][wave] = nll; sm[1][wave] = s1; sm[2][wave] = s2; }
    __syncthreads();
    if (threadIdx.x == 0) {
        f32x4 o;
        o.x = sm[0][0] + sm[0][1] + sm[0][2] + sm[0][3];
        o.y = sm[1][0] + sm[1][1] + sm[1][2] + sm[1][3];
        o.z = sm[2][0] + sm[2][1] + sm[2][2] + sm[2][3];
        o.w = 0.0f;
        *(f32x4*)(part + (size_t)blockIdx.x * 4) = o;  // 16B aligned slot
    }
}

// Reduce per-block partials, apply mean + regularizer. One block, 256 threads.
// Poison-safe: reads exactly the nblocks slots reduce_all fully wrote.
__global__ void finalize(const float* __restrict__ part, float* __restrict__ out,
                         float invN, int nblocks) {
    float nll = 0.0f, s1 = 0.0f, s2 = 0.0f;
    for (int i = threadIdx.x; i < nblocks; i += 256) {
        const f32x4 v = *(const f32x4*)(part + (size_t)i * 4);
        nll += v.x; s1 += v.y; s2 += v.z;
    }
    nll = wave_reduce(nll);
    s1  = wave_reduce(s1);
    s2  = wave_reduce(s2);

    __shared__ float sm[3][4];
    const int lane = threadIdx.x & 63;
    const int wave = threadIdx.x >> 6;
    if (lane == 0) { sm[0][wave] = nll; sm[1][wave] = s1; sm[2][wave] = s2; }
    __syncthreads();
    if (threadIdx.x == 0) {
        float tn = sm[0][0] + sm[0][1] + sm[0][2] + sm[0][3];
        float t1 = sm[1][0] + sm[1][1] + sm[1][2] + sm[1][3];
        float t2 = sm[2][0] + sm[2][1] + sm[2][2] + sm[2][3];
        out[0] = tn * invN + REGf * (sqrtf(t1) + sqrtf(t2));
    }
}

extern "C" void kernel_launch(void* const* d_in, const int* in_sizes, int n_in,
                              void* d_out, int out_size, void* d_ws, size_t ws_size,
                              hipStream_t stream) {
    const float* out1  = (const float*)d_in[0];   // [N,1] fp32
    const int*   label = (const int*)d_in[1];     // [N] int32 (jax x64 off)
    const float* W1    = (const float*)d_in[2];   // [1024,4096] fp32
    const float* W2    = (const float*)d_in[3];   // [4096,1024] fp32

    const int N  = in_sizes[0];
    const int n4 = N / 4;
    const int w4 = in_sizes[2] / 4;               // W1 and W2 same size

    const int NBLK = 1024;                        // R0's proven config: 4 blocks/CU
    float* part = (float*)d_ws;                   // NBLK * 4 floats = 16 KB

    // N-loop = 16 iters/thread (4 unrolled batches), W-loop = 1 batch.
    reduce_all<<<NBLK, 256, 0, stream>>>(
        (const f32x4*)out1, (const i32x4*)label,
        (const f32x4*)W1,   (const f32x4*)W2,
        part, n4, w4);
    finalize<<<1, 256, 0, stream>>>(part, (float*)d_out, 1.0f / (float)N, NBLK);
}

// Round 6
// 165.755 us; speedup vs baseline: 1.1680x; 1.0025x over previous
//
#include <hip/hip_runtime.h>
#include <math.h>

#define NEAR0f 1e-8f
#define REGf   0.002f

typedef float __attribute__((ext_vector_type(4))) f32x4;
typedef int   __attribute__((ext_vector_type(4))) i32x4;

__device__ __forceinline__ f32x4 ntload(const f32x4* p) { return __builtin_nontemporal_load(p); }
__device__ __forceinline__ i32x4 ntload(const i32x4* p) { return __builtin_nontemporal_load(p); }

__device__ __forceinline__ float wave_reduce(float v) {
#pragma unroll
    for (int off = 32; off > 0; off >>= 1)
        v += __shfl_down(v, off, 64);
    return v;
}

// sum of log(selected prob) over 4 elements, tree-summed
__device__ __forceinline__ float nll4(f32x4 p, i32x4 l) {
    float a0 = l.x ? p.x : 1.0f - p.x;
    float a1 = l.y ? p.y : 1.0f - p.y;
    float a2 = l.z ? p.z : 1.0f - p.z;
    float a3 = l.w ? p.w : 1.0f - p.w;
    float g0 = __logf(fmaxf(a0, NEAR0f)) + __logf(fmaxf(a1, NEAR0f));
    float g1 = __logf(fmaxf(a2, NEAR0f)) + __logf(fmaxf(a3, NEAR0f));
    return g0 + g1;
}

__device__ __forceinline__ float sq4(f32x4 a, float acc) {
    return fmaf(a.x, a.x, fmaf(a.y, a.y, fmaf(a.z, a.z, fmaf(a.w, a.w, acc))));
}

// R6: R5 shell+body frozen (best: 166.2 us total, reduce_all < 40.4 us),
// single lever = grid 1024 -> 2048.
// Session model (R0-R5 evidence):
//  - The harness's 256 MiB ws poison fill (fillBufferAligned, ~42 us @
//    6.5 TB/s) dirties the ENTIRE Infinity Cache before every launch.
//    Non-nt reads write-allocate and drag dirty-line writebacks -> every
//    no-nt round was slow (R1 63, R3 74, R4 77); every nt round fast
//    (R0 59-with-atomic-tail, R5 <40). KEEP ntload.
//  - Per-block partials shell (no init launch, no same-line atomic tail)
//    was worth ~20 us over atomicAdd shell at identical body.
//  - Grid size was never tested WITH nt (R1's 2048-block "failure" was the
//    missing nt). nt reads ~ HBM latency bound -> throughput scales with
//    outstanding bytes -> 8 waves/SIMD instead of 4.
// Fill proves the memory system sustains 6.5 TB/s; floor = 160 MiB ~ 27 us.
__global__ __launch_bounds__(256) void reduce_all(
    const f32x4* __restrict__ p4,
    const i32x4* __restrict__ l4,
    const f32x4* __restrict__ w1,
    const f32x4* __restrict__ w2,
    float* __restrict__ part,
    int n4, int w4)
{
    const int tid    = blockIdx.x * blockDim.x + threadIdx.x;
    const int stride = gridDim.x * blockDim.x;

    float nll0 = 0.0f, nll1 = 0.0f, nll2 = 0.0f, nll3 = 0.0f;
    int i = tid;
    for (; i + 3 * stride < n4; i += 4 * stride) {
        f32x4 p0 = ntload(p4 + i);
        f32x4 p1 = ntload(p4 + i + stride);
        f32x4 p2 = ntload(p4 + i + 2 * stride);
        f32x4 p3 = ntload(p4 + i + 3 * stride);
        i32x4 l0 = ntload(l4 + i);
        i32x4 l1 = ntload(l4 + i + stride);
        i32x4 l2 = ntload(l4 + i + 2 * stride);
        i32x4 l3 = ntload(l4 + i + 3 * stride);
        nll0 -= nll4(p0, l0);
        nll1 -= nll4(p1, l1);
        nll2 -= nll4(p2, l2);
        nll3 -= nll4(p3, l3);
    }
    for (; i < n4; i += stride) {
        nll0 -= nll4(ntload(p4 + i), ntload(l4 + i));
    }
    float nll = (nll0 + nll1) + (nll2 + nll3);

    float s1a = 0.0f, s1b = 0.0f, s2a = 0.0f, s2b = 0.0f;
    int j = tid;
    for (; j + 3 * stride < w4; j += 4 * stride) {
        f32x4 a0 = ntload(w1 + j);
        f32x4 a1 = ntload(w1 + j + stride);
        f32x4 a2 = ntload(w1 + j + 2 * stride);
        f32x4 a3 = ntload(w1 + j + 3 * stride);
        f32x4 b0 = ntload(w2 + j);
        f32x4 b1 = ntload(w2 + j + stride);
        f32x4 b2 = ntload(w2 + j + 2 * stride);
        f32x4 b3 = ntload(w2 + j + 3 * stride);
        s1a = sq4(a0, s1a); s1b = sq4(a1, s1b);
        s1a = sq4(a2, s1a); s1b = sq4(a3, s1b);
        s2a = sq4(b0, s2a); s2b = sq4(b1, s2b);
        s2a = sq4(b2, s2a); s2b = sq4(b3, s2b);
    }
    for (; j < w4; j += stride) {
        s1a = sq4(ntload(w1 + j), s1a);
        s2a = sq4(ntload(w2 + j), s2a);
    }
    float s1 = s1a + s1b;
    float s2 = s2a + s2b;

    nll = wave_reduce(nll);
    s1  = wave_reduce(s1);
    s2  = wave_reduce(s2);

    __shared__ float sm[3][4];
    const int lane = threadIdx.x & 63;
    const int wave = threadIdx.x >> 6;
    if (lane == 0) { sm[0][wave] = nll; sm[1][wave] = s1; sm[2][wave] = s2; }
    __syncthreads();
    if (threadIdx.x == 0) {
        f32x4 o;
        o.x = sm[0][0] + sm[0][1] + sm[0][2] + sm[0][3];
        o.y = sm[1][0] + sm[1][1] + sm[1][2] + sm[1][3];
        o.z = sm[2][0] + sm[2][1] + sm[2][2] + sm[2][3];
        o.w = 0.0f;
        *(f32x4*)(part + (size_t)blockIdx.x * 4) = o;  // 16B aligned slot
    }
}

// Reduce per-block partials, apply mean + regularizer. One block, 256 threads.
// Poison-safe: reads exactly the nblocks slots reduce_all fully wrote.
__global__ void finalize(const float* __restrict__ part, float* __restrict__ out,
                         float invN, int nblocks) {
    float nll = 0.0f, s1 = 0.0f, s2 = 0.0f;
    for (int i = threadIdx.x; i < nblocks; i += 256) {
        const f32x4 v = *(const f32x4*)(part + (size_t)i * 4);
        nll += v.x; s1 += v.y; s2 += v.z;
    }
    nll = wave_reduce(nll);
    s1  = wave_reduce(s1);
    s2  = wave_reduce(s2);

    __shared__ float sm[3][4];
    const int lane = threadIdx.x & 63;
    const int wave = threadIdx.x >> 6;
    if (lane == 0) { sm[0][wave] = nll; sm[1][wave] = s1; sm[2][wave] = s2; }
    __syncthreads();
    if (threadIdx.x == 0) {
        float tn = sm[0][0] + sm[0][1] + sm[0][2] + sm[0][3];
        float t1 = sm[1][0] + sm[1][1] + sm[1][2] + sm[1][3];
        float t2 = sm[2][0] + sm[2][1] + sm[2][2] + sm[2][3];
        out[0] = tn * invN + REGf * (sqrtf(t1) + sqrtf(t2));
    }
}

extern "C" void kernel_launch(void* const* d_in, const int* in_sizes, int n_in,
                              void* d_out, int out_size, void* d_ws, size_t ws_size,
                              hipStream_t stream) {
    const float* out1  = (const float*)d_in[0];   // [N,1] fp32
    const int*   label = (const int*)d_in[1];     // [N] int32 (jax x64 off)
    const float* W1    = (const float*)d_in[2];   // [1024,4096] fp32
    const float* W2    = (const float*)d_in[3];   // [4096,1024] fp32

    const int N  = in_sizes[0];
    const int n4 = N / 4;
    const int w4 = in_sizes[2] / 4;               // W1 and W2 same size

    const int NBLK = 2048;                        // 8 blocks/CU, 32 waves/CU
    float* part = (float*)d_ws;                   // NBLK * 4 floats = 32 KB

    // N-loop: 8 iters/thread (2 unrolled batches); W-loop: 2 tail iters.
    reduce_all<<<NBLK, 256, 0, stream>>>(
        (const f32x4*)out1, (const i32x4*)label,
        (const f32x4*)W1,   (const f32x4*)W2,
        part, n4, w4);
    finalize<<<1, 256, 0, stream>>>(part, (float*)d_out, 1.0f / (float)N, NBLK);
}